// Round 9
// baseline (250.256 us; speedup 1.0000x reference)
//
#include <hip/hip_runtime.h>

#define BATCH 8
#define CIN   64
#define COUT  64
#define HDIM  128
#define WDIM  128
#define HW    (HDIM * WDIM)
#define KK    9

typedef __attribute__((ext_vector_type(8)))  short  short8v;
typedef __attribute__((ext_vector_type(8)))  __bf16 bf16x8;
typedef __attribute__((ext_vector_type(16))) float  f32x16;
typedef float __attribute__((ext_vector_type(2), aligned(4))) float2u;

__device__ __forceinline__ short f2bf(float f) {   // fp32 -> bf16 RNE
    unsigned u = __float_as_uint(f);
    return (short)((u + 0x7fffu + ((u >> 16) & 1u)) >> 16);
}
__device__ __forceinline__ float bf2f(short s) {
    return __uint_as_float(((unsigned)(unsigned short)s) << 16);
}
__device__ __forceinline__ f32x16 mfma_bf16(short8v a, short8v b, f32x16 c) {
    return __builtin_amdgcn_mfma_f32_32x32x16_bf16(
        __builtin_bit_cast(bf16x8, a), __builtin_bit_cast(bf16x8, b), c, 0, 0, 0);
}

// ---------------------------------------------------------------------------
// W prep: weight [oc][c][3][3] -> MFMA A-operand frags, split bf16 hi/lo.
// K-order: s = cg*9 + t. Lane l: A[oc = mt*32+(l&31)][c = cg*16+(l>>5)*8+e].
// ---------------------------------------------------------------------------
__global__ __launch_bounds__(64) void wprep_kernel(
    const float* __restrict__ w, short* __restrict__ Wf)
{
    const int l   = threadIdx.x;
    const int blk = blockIdx.x;          // 0..71
    const int mt  = blk & 1;
    const int s   = blk >> 1;            // 0..35
    const int cg  = s / 9;
    const int t   = s - cg * 9;
    const int oc  = mt * 32 + (l & 31);
    const int cb  = cg * 16 + (l >> 5) * 8;
    short* p0 = Wf + ((size_t)blk * 2 + 0) * 512 + l * 8;
    short* p1 = Wf + ((size_t)blk * 2 + 1) * 512 + l * 8;
#pragma unroll
    for (int e = 0; e < 8; ++e) {
        float v = w[((size_t)oc * CIN + (cb + e)) * KK + t];
        short h = f2bf(v);
        p0[e] = h;
        p1[e] = f2bf(v - bf2f(h));
    }
}

// ---------------------------------------------------------------------------
// Kernel A v4: offset conv, 4-channels-per-step double-buffered pipeline.
// Block = 256 px (2 rows), parity split, b = lin&7 (XCD-pinned).
// Per step: issue next 4-channel group (4 float2/thread, in flight across
// 324 FMA), compute current group from LDS, write, 1 barrier (16 total).
// ---------------------------------------------------------------------------
__global__ __launch_bounds__(256) void offset_conv_kernel(
    const float* __restrict__ x,
    const float* __restrict__ ow,   // [18][64][3][3]
    const float* __restrict__ ob,   // [18]
    float* __restrict__ py,         // [B][KK][HW]
    float* __restrict__ px)
{
    __shared__ float Xs[2][4][4][132];  // [buf][ch-in-grp][row][col -1..130]

    const int tid = threadIdx.x;
    const int lin = blockIdx.x;          // 0..1023
    const int b   = lin & 7;             // XCD-aligned batch
    const int par = (lin >> 3) & 1;      // 0: dy/py, 1: dx/px
    const int pg  = lin >> 4;            // 0..63
    const int h0  = pg * 2;
    const int hh  = tid >> 7;            // 0/1: row within pair
    const int w   = tid & 127;

    // zero the x-halo once (cols 1 and 130 per [buf][ch][row])
    if (tid < 64) {
        const int bu = tid >> 5, j = (tid >> 3) & 3, r = (tid >> 1) & 3, side = tid & 1;
        Xs[bu][j][r][1 + side * 129] = 0.0f;
    }

    float acc[9];
#pragma unroll
    for (int i = 0; i < 9; ++i) acc[i] = ob[2 * i + par];

    const float* xb = x + (size_t)b * CIN * HW;

    const int st_r   = tid >> 6;         // 0..3 staging row
    const int st_col = (tid * 2) & 127;
    const int st_y   = h0 - 1 + st_r;
    const bool st_v  = (unsigned)st_y < (unsigned)HDIM;
    const float* st_src = xb + (size_t)st_y * WDIM + st_col;

    float2 ld[4];
    auto issue = [&](int g) {
#pragma unroll
        for (int j = 0; j < 4; ++j)
            ld[j] = st_v ? *(const float2*)(st_src + (size_t)(g * 4 + j) * HW)
                         : make_float2(0.0f, 0.0f);
    };
    auto write = [&](int bu) {
#pragma unroll
        for (int j = 0; j < 4; ++j)
            *(float2*)&Xs[bu][j][st_r][2 + st_col] = ld[j];
    };

    issue(0);
    write(0);
    __syncthreads();

    for (int g = 0; g < 16; ++g) {       // 16 groups of 4 channels
        const int bu = g & 1;
        if (g + 1 < 16) issue(g + 1);

#pragma unroll
        for (int j = 0; j < 4; ++j) {
            const int c = g * 4 + j;
            float tv[9];
#pragma unroll
            for (int di = 0; di < 3; ++di)
#pragma unroll
                for (int dj = 0; dj < 3; ++dj)
                    tv[di * 3 + dj] = Xs[bu][j][hh + di][w + dj + 1];

            const float* wb = ow + (size_t)par * (CIN * 9) + c * 9;
#pragma unroll
            for (int i = 0; i < 9; ++i) {
                const float* wp = wb + (size_t)i * (2 * CIN * 9);  // oc = 2i+par
#pragma unroll
                for (int t = 0; t < 9; ++t) acc[i] = fmaf(tv[t], wp[t], acc[i]);
            }
        }

        if (g + 1 < 16) write(bu ^ 1);
        __syncthreads();
    }

    const int pixel = pg * 256 + tid;
    float* dst = par ? px : py;
#pragma unroll
    for (int i = 0; i < 9; ++i) {
        const int ki = i / 3, kj = i % 3;
        const float base = par ? (float)(w - 1 + kj) : (float)((h0 + hh) - 1 + ki);
        dst[((size_t)b * KK + i) * HW + pixel] = base + acc[i];
    }
}

// ---------------------------------------------------------------------------
// Kernel B v9: 2 output rows per block share one 9-row LDS window.
// Grid 512 (b=blk&7 XCD-pinned, h0=(blk>>3)*2); 512 thr = 8 waves.
// Wave w: output row h0+(w>>2), px N-tile 32*(w&3). Window rows [h0-3,h0+5]
// x 16 ch fp32 (72 KB), staged per c-group; lane samples its own B-frag into
// registers; per-lane global-gather fallback if sample leaves window.
// 16 waves/CU (2 blocks) vs 8 before -> latency hiding doubles.
// ---------------------------------------------------------------------------
__global__ __launch_bounds__(512)
__attribute__((amdgpu_waves_per_eu(4, 4)))
void deform_mfma_kernel(
    const float* __restrict__ x,
    const short* __restrict__ Wf,
    const float* __restrict__ py,
    const float* __restrict__ px_,
    float* __restrict__ out)
{
    __shared__ float Xw[9][16][128];     // 72 KB fp32 sampling window

    const int tid = threadIdx.x;
    const int blk = blockIdx.x;
    const int b   = blk & 7;             // XCD-aligned batch
    const int h0  = (blk >> 3) * 2;      // row pair base
    const int l   = tid & 63;
    const int wv  = tid >> 6;            // 0..7
    const int hrow = h0 + (wv >> 2);     // this wave's output row
    const int mypx = 32 * (wv & 3) + (l & 31);
    const int ch8  = (l >> 5) * 8;

    f32x16 acc0, acc1;
#pragma unroll
    for (int i = 0; i < 16; ++i) { acc0[i] = 0.f; acc1[i] = 0.f; }

    const float* xb = x + (size_t)b * CIN * HW;
    const float* pyb = py  + (size_t)b * KK * HW + hrow * WDIM + mypx;
    const float* pxb = px_ + (size_t)b * KK * HW + hrow * WDIM + mypx;

    // stage c-group cg: 9 float4 per thread over [9][16][32] float4s
    auto stage = [&](int cg) {
#pragma unroll
        for (int i = 0; i < 9; ++i) {
            const int f = i * 512 + tid;        // 0..4607
            const int r   = f >> 9;             // 0..8
            const int c   = (f >> 5) & 15;
            const int col = (f & 31) * 4;
            const int y = h0 - 3 + r;
            float4 v = make_float4(0.f, 0.f, 0.f, 0.f);
            if ((unsigned)y < (unsigned)HDIM)
                v = *(const float4*)(xb + (size_t)(cg * 16 + c) * HW + y * WDIM + col);
            *(float4*)&Xw[r][c][col] = v;
        }
    };

    float pyc = pyb[0], pxc = pxb[0];    // tap-0 positions

    for (int cg = 0; cg < 4; ++cg) {
        __syncthreads();                 // prev window fully consumed
        stage(cg);
        __syncthreads();

        for (int t = 0; t < 9; ++t) {
            const int s = cg * 9 + t;

            // W frags (global, L2-hot) — issue early
            const short* wf = Wf + (size_t)(s * 4) * 512;
            const short8v w0h = *(const short8v*)(wf + 0 * 512 + l * 8);
            const short8v w0l = *(const short8v*)(wf + 1 * 512 + l * 8);
            const short8v w1h = *(const short8v*)(wf + 2 * 512 + l * 8);
            const short8v w1l = *(const short8v*)(wf + 3 * 512 + l * 8);

            // ---- sampling params for this lane's pixel
            const float y0f = floorf(pyc), x0f = floorf(pxc);
            const float fy = pyc - y0f, fx = pxc - x0f;
            const int y0 = (int)y0f, x0 = (int)x0f;
            const bool vy0 = (unsigned)y0 < (unsigned)HDIM;
            const bool vy1 = (unsigned)(y0 + 1) < (unsigned)HDIM;
            const bool vx0 = (unsigned)x0 < (unsigned)WDIM;
            const bool vx1 = (unsigned)(x0 + 1) < (unsigned)WDIM;
            const int cy0 = min(max(y0, 0), HDIM - 1);
            const int cy1 = min(max(y0 + 1, 0), HDIM - 1);
            const int axc = min(max(x0, 0), WDIM - 2);
            const float wxL = vx0 ? (1.f - fx) : 0.f;
            const float wxR = vx1 ? fx : 0.f;
            float cgx, cgy;
            if (x0 < 0)              { cgx = wxR; cgy = 0.f; }
            else if (x0 >= WDIM - 1) { cgx = 0.f; cgy = wxL; }
            else                     { cgx = wxL; cgy = wxR; }
            const float wy0v = vy0 ? (1.f - fy) : 0.f;
            const float wy1v = vy1 ? fy : 0.f;
            const float a0  = wy0v * cgx, b0c = wy0v * cgy;
            const float a2  = wy1v * cgx, b2c = wy1v * cgy;

            // prefetch next tap's positions
            const int t2 = (t + 1) % 9;
            pyc = pyb[(size_t)t2 * HW];
            pxc = pxb[(size_t)t2 * HW];

            const int r0 = cy0 - (h0 - 3), r1 = cy1 - (h0 - 3);
            const bool oob = ((unsigned)r0 > 8u) | ((unsigned)r1 > 8u);

            // ---- sample this lane's 8 channels
            float v[8];
            if (!oob) {
#pragma unroll
                for (int e = 0; e < 8; ++e) {
                    const float2u p0 = *(const float2u*)&Xw[r0][ch8 + e][axc];
                    const float2u p1 = *(const float2u*)&Xw[r1][ch8 + e][axc];
                    float s0 = p0.x * a0;
                    s0 = fmaf(p0.y, b0c, s0);
                    s0 = fmaf(p1.x, a2,  s0);
                    s0 = fmaf(p1.y, b2c, s0);
                    v[e] = s0;
                }
            } else {                         // statistically-never global path
                const int cbase = cg * 16 + ch8;
#pragma unroll
                for (int e = 0; e < 8; ++e) {
                    const float* xc = xb + (size_t)(cbase + e) * HW;
                    float s0 = xc[cy0 * WDIM + axc] * a0;
                    s0 = fmaf(xc[cy0 * WDIM + axc + 1], b0c, s0);
                    s0 = fmaf(xc[cy1 * WDIM + axc],     a2,  s0);
                    s0 = fmaf(xc[cy1 * WDIM + axc + 1], b2c, s0);
                    v[e] = s0;
                }
            }

            // ---- split bf16 hi/lo, pack
            short8v bh, bl;
#pragma unroll
            for (int e = 0; e < 8; ++e) {
                const short hs = f2bf(v[e]);
                bh[e] = hs;
                bl[e] = f2bf(v[e] - bf2f(hs));
            }

            acc0 = mfma_bf16(w0h, bh, acc0);
            acc1 = mfma_bf16(w1h, bh, acc1);
            acc0 = mfma_bf16(w0l, bh, acc0);
            acc1 = mfma_bf16(w1l, bh, acc1);
            acc0 = mfma_bf16(w0h, bl, acc0);
            acc1 = mfma_bf16(w1h, bl, acc1);
        }
    }

    // ---- epilogue: col=lane&31 (px), row=(r&3)+8*(r>>2)+4*(l>>5)
    float* ob = out + (size_t)b * COUT * HW + (size_t)hrow * WDIM
              + 32 * (wv & 3) + (l & 31);
#pragma unroll
    for (int r = 0; r < 16; ++r) {
        const int oc0 = (r & 3) + 8 * (r >> 2) + 4 * (l >> 5);
        ob[(size_t)oc0 * HW]        = acc0[r];
        ob[(size_t)(oc0 + 32) * HW] = acc1[r];
    }
}

// ---------------------------------------------------------------------------
extern "C" void kernel_launch(void* const* d_in, const int* in_sizes, int n_in,
                              void* d_out, int out_size, void* d_ws, size_t ws_size,
                              hipStream_t stream)
{
    const float* x   = (const float*)d_in[0];
    const float* ow  = (const float*)d_in[1];
    const float* obi = (const float*)d_in[2];
    const float* wgt = (const float*)d_in[3];
    float* out = (float*)d_out;

    // ws layout: py | px | Wf (bf16 frags)
    float* pyw = (float*)d_ws;
    float* pxw = pyw + (size_t)BATCH * KK * HW;
    short* Wf  = (short*)(pxw + (size_t)BATCH * KK * HW);

    wprep_kernel<<<dim3(72), 64, 0, stream>>>(wgt, Wf);
    offset_conv_kernel<<<dim3(1024), 256, 0, stream>>>(x, ow, obi, pyw, pxw);
    deform_mfma_kernel<<<dim3(512), 512, 0, stream>>>(x, Wf, pyw, pxw, out);
}

// Round 10
// 183.137 us; speedup vs baseline: 1.3665x; 1.3665x over previous
//
#include <hip/hip_runtime.h>

#define BATCH 8
#define CIN   64
#define COUT  64
#define HDIM  128
#define WDIM  128
#define HW    (HDIM * WDIM)
#define KK    9

typedef __attribute__((ext_vector_type(8)))  short  short8v;
typedef __attribute__((ext_vector_type(8)))  __bf16 bf16x8;
typedef __attribute__((ext_vector_type(16))) float  f32x16;
typedef float __attribute__((ext_vector_type(2), aligned(4))) float2u;

__device__ __forceinline__ short f2bf(float f) {   // fp32 -> bf16 RNE
    unsigned u = __float_as_uint(f);
    return (short)((u + 0x7fffu + ((u >> 16) & 1u)) >> 16);
}
__device__ __forceinline__ float bf2f(short s) {
    return __uint_as_float(((unsigned)(unsigned short)s) << 16);
}
__device__ __forceinline__ f32x16 mfma_bf16(short8v a, short8v b, f32x16 c) {
    return __builtin_amdgcn_mfma_f32_32x32x16_bf16(
        __builtin_bit_cast(bf16x8, a), __builtin_bit_cast(bf16x8, b), c, 0, 0, 0);
}

// ---------------------------------------------------------------------------
// W prep (main conv): weight [oc][c][3][3] -> MFMA A-frags, split bf16 hi/lo.
// K-order: s = cg*9 + t. Lane l: A[oc = mt*32+(l&31)][c = cg*16+(l>>5)*8+e].
// ---------------------------------------------------------------------------
__global__ __launch_bounds__(64) void wprep_kernel(
    const float* __restrict__ w, short* __restrict__ Wf)
{
    const int l   = threadIdx.x;
    const int blk = blockIdx.x;          // 0..71
    const int mt  = blk & 1;
    const int s   = blk >> 1;            // 0..35
    const int cg  = s / 9;
    const int t   = s - cg * 9;
    const int oc  = mt * 32 + (l & 31);
    const int cb  = cg * 16 + (l >> 5) * 8;
    short* p0 = Wf + ((size_t)blk * 2 + 0) * 512 + l * 8;
    short* p1 = Wf + ((size_t)blk * 2 + 1) * 512 + l * 8;
#pragma unroll
    for (int e = 0; e < 8; ++e) {
        float v = w[((size_t)oc * CIN + (cb + e)) * KK + t];
        short h = f2bf(v);
        p0[e] = h;
        p1[e] = f2bf(v - bf2f(h));
    }
}

// ---------------------------------------------------------------------------
// W prep (offset conv): offset_w [18][64][3][3] -> A-frags (M=32, 18 real),
// plain bf16. Wo[s][lane*8+e], s = cg*9 + t.
// ---------------------------------------------------------------------------
__global__ __launch_bounds__(64) void wprep_off_kernel(
    const float* __restrict__ ow, short* __restrict__ Wo)
{
    const int l  = threadIdx.x;
    const int s  = blockIdx.x;           // 0..35
    const int cg = s / 9;
    const int t  = s - cg * 9;
    const int oc = l & 31;
    const int cb = cg * 16 + (l >> 5) * 8;
    short* p = Wo + (size_t)s * 512 + l * 8;
#pragma unroll
    for (int e = 0; e < 8; ++e) {
        float v = (oc < 18) ? ow[((size_t)oc * CIN + (cb + e)) * KK + t] : 0.0f;
        p[e] = f2bf(v);
    }
}

// ---------------------------------------------------------------------------
// Kernel A v5: offset conv as MFMA implicit GEMM, writing py/px directly.
// Grid 1024 (b=blk&7 XCD-pinned, h=blk>>3); 256 thr = 4 waves.
// out[18][128px] = Wo[18,576] x im2col(x); window [3 rows][16 ch][136] fp32
// (25.5 KB, halo zeroed -> no bounds checks); per K-step: 8 ds_read_b32 +
// bf16 pack + 1 MFMA. Epilogue: py/px = base_grid + out + bias from C-frag.
// ---------------------------------------------------------------------------
__global__ __launch_bounds__(256) void offset_conv_kernel(
    const float* __restrict__ x,
    const short* __restrict__ Wo,
    const float* __restrict__ ob,   // [18]
    float* __restrict__ py,         // [B][KK][HW]
    float* __restrict__ px)
{
    __shared__ float Xo[3][16][136];     // 25.5 KB; data at [4+col]

    const int tid = threadIdx.x;
    const int blk = blockIdx.x;
    const int b   = blk & 7;             // XCD-aligned batch
    const int h   = blk >> 3;            // output row
    const int l   = tid & 63;
    const int wv  = tid >> 6;            // 0..3: px N-tile
    const int pcol = 32 * wv + (l & 31); // this lane's pixel column
    const int ch8  = (l >> 5) * 8;

    f32x16 acc;
#pragma unroll
    for (int i = 0; i < 16; ++i) acc[i] = 0.f;

    const float* xb = x + (size_t)b * CIN * HW;

    // zero the x-halo (idx 3 => col -1, idx 132 => col 128), 96 floats
    if (tid < 96) {
        const int r = tid >> 5, cc = (tid >> 1) & 15, side = tid & 1;
        Xo[r][cc][3 + side * 129] = 0.0f;
    }

    // stage c-group: 6 float4/thread over [3][16][32]-float4s, rows h-1..h+1
    auto stage = [&](int cg) {
#pragma unroll
        for (int i = 0; i < 6; ++i) {
            const int f = i * 256 + tid;        // 0..1535
            const int r   = f >> 9;             // 0..2
            const int cc  = (f >> 5) & 15;
            const int col = (f & 31) * 4;
            const int y = h - 1 + r;
            float4 v = make_float4(0.f, 0.f, 0.f, 0.f);
            if ((unsigned)y < (unsigned)HDIM)
                v = *(const float4*)(xb + (size_t)(cg * 16 + cc) * HW + y * WDIM + col);
            *(float4*)&Xo[r][cc][4 + col] = v;
        }
    };

    for (int cg = 0; cg < 4; ++cg) {
        __syncthreads();
        stage(cg);
        __syncthreads();

#pragma unroll
        for (int t = 0; t < 9; ++t) {
            const int s = cg * 9 + t;
            const short8v wo = *(const short8v*)(Wo + (size_t)s * 512 + l * 8);

            const int ki = t / 3, kj = t % 3;
            short8v bh;
#pragma unroll
            for (int e = 0; e < 8; ++e)
                bh[e] = f2bf(Xo[ki][ch8 + e][3 + pcol + kj]);

            acc = mfma_bf16(wo, bh, acc);
        }
    }

    // epilogue: C row = oc0 = (r&3)+8*(r>>2)+4*(l>>5); col = pcol.
    // oc0 = 2*kk + par; p = base + conv + bias.
#pragma unroll
    for (int r = 0; r < 16; ++r) {
        const int oc0 = (r & 3) + 8 * (r >> 2) + 4 * (l >> 5);
        if (oc0 < 18) {
            const int kk = oc0 >> 1, par = oc0 & 1;
            const float base = par ? (float)(pcol - 1 + (kk % 3))
                                   : (float)(h - 1 + (kk / 3));
            float* dst = (par ? px : py)
                       + ((size_t)b * KK + kk) * HW + h * WDIM + pcol;
            *dst = base + acc[r] + ob[oc0];
        }
    }
}

// ---------------------------------------------------------------------------
// Kernel B v8 (proven 92 us, reverted verbatim): in-register sampling from an
// 8-row LDS window + split-bf16 MFMA. Grid 1024 (b=blk&7, h=blk>>3), 4 waves.
// ---------------------------------------------------------------------------
__global__ __launch_bounds__(256)
__attribute__((amdgpu_waves_per_eu(2, 4)))
void deform_mfma_kernel(
    const float* __restrict__ x,
    const short* __restrict__ Wf,
    const float* __restrict__ py,
    const float* __restrict__ px_,
    float* __restrict__ out)
{
    __shared__ float Xw[8][16][128];     // 64 KB fp32 sampling window

    const int tid = threadIdx.x;
    const int blk = blockIdx.x;
    const int b  = blk & 7;              // XCD-aligned batch
    const int h  = blk >> 3;             // output row
    const int l  = tid & 63;
    const int wv = tid >> 6;             // wave id = px N-tile
    const int mypx = 32 * wv + (l & 31); // this lane's pixel
    const int ch8  = (l >> 5) * 8;       // this lane's channel sub-base

    f32x16 acc0, acc1;
#pragma unroll
    for (int i = 0; i < 16; ++i) { acc0[i] = 0.f; acc1[i] = 0.f; }

    const float* xb = x + (size_t)b * CIN * HW;
    const float* pyb = py  + (size_t)b * KK * HW + h * WDIM + mypx;
    const float* pxb = px_ + (size_t)b * KK * HW + h * WDIM + mypx;

    auto stage = [&](int cg) {
#pragma unroll
        for (int i = 0; i < 16; ++i) {
            const int f = i * 256 + tid;        // float4 idx over [8][16][32]
            const int r   = f >> 9;             // 0..7
            const int c   = (f >> 5) & 15;
            const int col = (f & 31) * 4;
            const int y = h - 3 + r;
            float4 v = make_float4(0.f, 0.f, 0.f, 0.f);
            if ((unsigned)y < (unsigned)HDIM)
                v = *(const float4*)(xb + (size_t)(cg * 16 + c) * HW + y * WDIM + col);
            *(float4*)&Xw[r][c][col] = v;
        }
    };

    float pyc = pyb[0], pxc = pxb[0];    // tap-0 positions

    for (int cg = 0; cg < 4; ++cg) {
        __syncthreads();                 // prev window fully consumed
        stage(cg);
        __syncthreads();

        for (int t = 0; t < 9; ++t) {
            const int s = cg * 9 + t;

            // W frags for this K-step (global, L2-hot) — issue early
            const short* wf = Wf + (size_t)(s * 4) * 512;
            const short8v w0h = *(const short8v*)(wf + 0 * 512 + l * 8);
            const short8v w0l = *(const short8v*)(wf + 1 * 512 + l * 8);
            const short8v w1h = *(const short8v*)(wf + 2 * 512 + l * 8);
            const short8v w1l = *(const short8v*)(wf + 3 * 512 + l * 8);

            // ---- sampling params for this lane's pixel
            const float y0f = floorf(pyc), x0f = floorf(pxc);
            const float fy = pyc - y0f, fx = pxc - x0f;
            const int y0 = (int)y0f, x0 = (int)x0f;
            const bool vy0 = (unsigned)y0 < (unsigned)HDIM;
            const bool vy1 = (unsigned)(y0 + 1) < (unsigned)HDIM;
            const bool vx0 = (unsigned)x0 < (unsigned)WDIM;
            const bool vx1 = (unsigned)(x0 + 1) < (unsigned)WDIM;
            const int cy0 = min(max(y0, 0), HDIM - 1);
            const int cy1 = min(max(y0 + 1, 0), HDIM - 1);
            const int axc = min(max(x0, 0), WDIM - 2);
            const float wxL = vx0 ? (1.f - fx) : 0.f;
            const float wxR = vx1 ? fx : 0.f;
            float cgx, cgy;
            if (x0 < 0)              { cgx = wxR; cgy = 0.f; }
            else if (x0 >= WDIM - 1) { cgx = 0.f; cgy = wxL; }
            else                     { cgx = wxL; cgy = wxR; }
            const float wy0v = vy0 ? (1.f - fy) : 0.f;
            const float wy1v = vy1 ? fy : 0.f;
            const float a0  = wy0v * cgx, b0c = wy0v * cgy;
            const float a2  = wy1v * cgx, b2c = wy1v * cgy;

            // prefetch next tap's positions
            const int t2 = (t + 1) % 9;
            pyc = pyb[(size_t)t2 * HW];
            pxc = pxb[(size_t)t2 * HW];

            const int r0 = cy0 - (h - 3), r1 = cy1 - (h - 3);
            const bool oob = ((unsigned)r0 > 7u) | ((unsigned)r1 > 7u);

            // ---- sample this lane's 8 channels
            float v[8];
            if (!oob) {
#pragma unroll
                for (int e = 0; e < 8; ++e) {
                    const float2u p0 = *(const float2u*)&Xw[r0][ch8 + e][axc];
                    const float2u p1 = *(const float2u*)&Xw[r1][ch8 + e][axc];
                    float s0 = p0.x * a0;
                    s0 = fmaf(p0.y, b0c, s0);
                    s0 = fmaf(p1.x, a2,  s0);
                    s0 = fmaf(p1.y, b2c, s0);
                    v[e] = s0;
                }
            } else {                         // statistically-never global path
                const int cbase = cg * 16 + ch8;
#pragma unroll
                for (int e = 0; e < 8; ++e) {
                    const float* xc = xb + (size_t)(cbase + e) * HW;
                    float s0 = xc[cy0 * WDIM + axc] * a0;
                    s0 = fmaf(xc[cy0 * WDIM + axc + 1], b0c, s0);
                    s0 = fmaf(xc[cy1 * WDIM + axc],     a2,  s0);
                    s0 = fmaf(xc[cy1 * WDIM + axc + 1], b2c, s0);
                    v[e] = s0;
                }
            }

            // ---- split bf16 hi/lo, pack to fragments
            short8v bh, bl;
#pragma unroll
            for (int e = 0; e < 8; ++e) {
                const short hs = f2bf(v[e]);
                bh[e] = hs;
                bl[e] = f2bf(v[e] - bf2f(hs));
            }

            acc0 = mfma_bf16(w0h, bh, acc0);
            acc1 = mfma_bf16(w1h, bh, acc1);
            acc0 = mfma_bf16(w0l, bh, acc0);
            acc1 = mfma_bf16(w1l, bh, acc1);
            acc0 = mfma_bf16(w0h, bl, acc0);
            acc1 = mfma_bf16(w1h, bl, acc1);
        }
    }

    // ---- epilogue: col=lane&31 (px), row=(r&3)+8*(r>>2)+4*(l>>5)
    float* ob = out + (size_t)b * COUT * HW + h * WDIM + 32 * wv + (l & 31);
#pragma unroll
    for (int r = 0; r < 16; ++r) {
        const int oc0 = (r & 3) + 8 * (r >> 2) + 4 * (l >> 5);
        ob[(size_t)oc0 * HW]        = acc0[r];
        ob[(size_t)(oc0 + 32) * HW] = acc1[r];
    }
}

// ---------------------------------------------------------------------------
extern "C" void kernel_launch(void* const* d_in, const int* in_sizes, int n_in,
                              void* d_out, int out_size, void* d_ws, size_t ws_size,
                              hipStream_t stream)
{
    const float* x   = (const float*)d_in[0];
    const float* ow  = (const float*)d_in[1];
    const float* obi = (const float*)d_in[2];
    const float* wgt = (const float*)d_in[3];
    float* out = (float*)d_out;

    // ws layout: py | px | Wf (144 KB) | Wo (36 KB)
    float* pyw = (float*)d_ws;
    float* pxw = pyw + (size_t)BATCH * KK * HW;
    short* Wf  = (short*)(pxw + (size_t)BATCH * KK * HW);
    short* Wo  = Wf + (size_t)72 * 2 * 512;

    wprep_kernel<<<dim3(72), 64, 0, stream>>>(wgt, Wf);
    wprep_off_kernel<<<dim3(36), 64, 0, stream>>>(ow, Wo);
    offset_conv_kernel<<<dim3(1024), 256, 0, stream>>>(x, Wo, obi, pyw, pxw);
    deform_mfma_kernel<<<dim3(1024), 256, 0, stream>>>(x, Wf, pyw, pxw, out);
}

// Round 11
// 174.609 us; speedup vs baseline: 1.4332x; 1.0488x over previous
//
#include <hip/hip_runtime.h>

#define BATCH 8
#define CIN   64
#define COUT  64
#define HDIM  128
#define WDIM  128
#define HW    (HDIM * WDIM)
#define KK    9

typedef __attribute__((ext_vector_type(8)))  short  short8v;
typedef __attribute__((ext_vector_type(8)))  __bf16 bf16x8;
typedef __attribute__((ext_vector_type(16))) float  f32x16;
typedef float __attribute__((ext_vector_type(2), aligned(4))) float2u;

__device__ __forceinline__ short f2bf(float f) {   // fp32 -> bf16 RNE
    unsigned u = __float_as_uint(f);
    return (short)((u + 0x7fffu + ((u >> 16) & 1u)) >> 16);
}
__device__ __forceinline__ float bf2f(short s) {
    return __uint_as_float(((unsigned)(unsigned short)s) << 16);
}
__device__ __forceinline__ f32x16 mfma_bf16(short8v a, short8v b, f32x16 c) {
    return __builtin_amdgcn_mfma_f32_32x32x16_bf16(
        __builtin_bit_cast(bf16x8, a), __builtin_bit_cast(bf16x8, b), c, 0, 0, 0);
}

// ---------------------------------------------------------------------------
// W prep (merged): blk<72 -> main-conv frags (split bf16 hi/lo, s=blk>>1,
// mt=blk&1); blk>=72 -> offset-conv frags (plain bf16, M=32 with 18 real).
// K-order for both: s = cg*9 + t. Lane l: c = cg*16 + (l>>5)*8 + e.
// ---------------------------------------------------------------------------
__global__ __launch_bounds__(64) void wprep_all_kernel(
    const float* __restrict__ w, const float* __restrict__ ow,
    short* __restrict__ Wf, short* __restrict__ Wo)
{
    const int l   = threadIdx.x;
    const int blk = blockIdx.x;          // 0..107
    if (blk < 72) {
        const int mt  = blk & 1;
        const int s   = blk >> 1;        // 0..35
        const int cg  = s / 9;
        const int t   = s - cg * 9;
        const int oc  = mt * 32 + (l & 31);
        const int cb  = cg * 16 + (l >> 5) * 8;
        short* p0 = Wf + ((size_t)blk * 2 + 0) * 512 + l * 8;
        short* p1 = Wf + ((size_t)blk * 2 + 1) * 512 + l * 8;
#pragma unroll
        for (int e = 0; e < 8; ++e) {
            float v = w[((size_t)oc * CIN + (cb + e)) * KK + t];
            short h = f2bf(v);
            p0[e] = h;
            p1[e] = f2bf(v - bf2f(h));
        }
    } else {
        const int s  = blk - 72;         // 0..35
        const int cg = s / 9;
        const int t  = s - cg * 9;
        const int oc = l & 31;
        const int cb = cg * 16 + (l >> 5) * 8;
        short* p = Wo + (size_t)s * 512 + l * 8;
#pragma unroll
        for (int e = 0; e < 8; ++e) {
            float v = (oc < 18) ? ow[((size_t)oc * CIN + (cb + e)) * KK + t] : 0.0f;
            p[e] = f2bf(v);
        }
    }
}

// ---------------------------------------------------------------------------
// Fused kernel: offset conv (phase A) + deformable sampling + main MFMA GEMM
// (phase B) in one block. Grid 1024 (b=blk&7 XCD-pinned, h=blk>>3), 4 waves.
//
// Phase A: out_off[18][128px] = Wo[18,576] x im2col(x) via MFMA; the 3-row
// window reuses Xw's LDS as [3][16][136] (zeroed halo). C-frag -> pos_lds
// [18][128] (+bias +base grid); each lane then pulls its own pixel's 18
// positions into registers (pyr/pxr[9]).
// Phase B: v8 sampler verbatim: 8-row window [h-3,h+4] x 16ch fp32 (64 KB),
// per-lane in-register B-frag sampling, split-bf16 hi/lo, 6 MFMA / K-step,
// per-lane global-gather fallback if a sample leaves the window.
// ---------------------------------------------------------------------------
__global__ __launch_bounds__(256)
__attribute__((amdgpu_waves_per_eu(2, 4)))
void fused_deform_kernel(
    const float* __restrict__ x,
    const short* __restrict__ Wf,
    const short* __restrict__ Wo,
    const float* __restrict__ ob,    // [18]
    float* __restrict__ out)
{
    __shared__ float Xw[8][16][128];     // 64 KB window (phase A reuses as [3][16][136])
    __shared__ float pos_lds[18][128];   //  9 KB  exchanged offset positions

    const int tid = threadIdx.x;
    const int blk = blockIdx.x;
    const int b  = blk & 7;              // XCD-aligned batch
    const int h  = blk >> 3;             // output row
    const int l  = tid & 63;
    const int wv = tid >> 6;             // wave id = px N-tile
    const int mypx = 32 * wv + (l & 31); // this lane's pixel (both phases)
    const int ch8  = (l >> 5) * 8;       // this lane's channel sub-base

    const float* xb = x + (size_t)b * CIN * HW;

    // ======================= Phase A: offset conv ==========================
    {
        float (*Xo)[16][136] = (float(*)[16][136]) & Xw[0][0][0];  // 25.5 KB

        if (tid < 96) {                  // zero x-halo (cols -1 and 128)
            const int r = tid >> 5, cc = (tid >> 1) & 15, side = tid & 1;
            Xo[r][cc][3 + side * 129] = 0.0f;
        }

        f32x16 aco;
#pragma unroll
        for (int i = 0; i < 16; ++i) aco[i] = 0.f;

        for (int cg = 0; cg < 4; ++cg) {
            __syncthreads();
            // stage rows h-1..h+1 x 16 ch (6 float4/thread, coalesced)
#pragma unroll
            for (int i = 0; i < 6; ++i) {
                const int f = i * 256 + tid;       // over [3][16][32] float4s
                const int r   = f >> 9;
                const int cc  = (f >> 5) & 15;
                const int col = (f & 31) * 4;
                const int y = h - 1 + r;
                float4 v = make_float4(0.f, 0.f, 0.f, 0.f);
                if ((unsigned)y < (unsigned)HDIM)
                    v = *(const float4*)(xb + (size_t)(cg * 16 + cc) * HW + y * WDIM + col);
                *(float4*)&Xo[r][cc][4 + col] = v;
            }
            __syncthreads();

#pragma unroll
            for (int t = 0; t < 9; ++t) {
                const int s = cg * 9 + t;
                const short8v wo = *(const short8v*)(Wo + (size_t)s * 512 + l * 8);
                const int ki = t / 3, kj = t % 3;
                short8v bh;
#pragma unroll
                for (int e = 0; e < 8; ++e)
                    bh[e] = f2bf(Xo[ki][ch8 + e][3 + mypx + kj]);
                aco = mfma_bf16(wo, bh, aco);
            }
        }

        // exchange: C row oc0=(r&3)+8*(r>>2)+4*(l>>5), col=mypx
#pragma unroll
        for (int r = 0; r < 16; ++r) {
            const int oc0 = (r & 3) + 8 * (r >> 2) + 4 * (l >> 5);
            if (oc0 < 18) {
                const int kk = oc0 >> 1, par = oc0 & 1;
                const float base = par ? (float)(mypx - 1 + (kk % 3))
                                       : (float)(h - 1 + (kk / 3));
                pos_lds[oc0][mypx] = base + aco[r] + ob[oc0];
            }
        }
        __syncthreads();
    }

    // pull this lane's 18 positions into registers
    float pyr[9], pxr[9];
#pragma unroll
    for (int k = 0; k < 9; ++k) {
        pyr[k] = pos_lds[2 * k][mypx];
        pxr[k] = pos_lds[2 * k + 1][mypx];
    }

    // ================== Phase B: sampler + main GEMM (v8) ==================
    f32x16 acc0, acc1;
#pragma unroll
    for (int i = 0; i < 16; ++i) { acc0[i] = 0.f; acc1[i] = 0.f; }

    for (int cg = 0; cg < 4; ++cg) {
        __syncthreads();                 // prev window fully consumed
#pragma unroll
        for (int i = 0; i < 16; ++i) {   // stage 8-row window
            const int f = i * 256 + tid;        // float4 idx over [8][16][32]
            const int r   = f >> 9;
            const int c   = (f >> 5) & 15;
            const int col = (f & 31) * 4;
            const int y = h - 3 + r;
            float4 v = make_float4(0.f, 0.f, 0.f, 0.f);
            if ((unsigned)y < (unsigned)HDIM)
                v = *(const float4*)(xb + (size_t)(cg * 16 + c) * HW + y * WDIM + col);
            *(float4*)&Xw[r][c][col] = v;
        }
        __syncthreads();

        for (int t = 0; t < 9; ++t) {
            const int s = cg * 9 + t;

            // W frags for this K-step (global, L2-hot) — issue early
            const short* wf = Wf + (size_t)(s * 4) * 512;
            const short8v w0h = *(const short8v*)(wf + 0 * 512 + l * 8);
            const short8v w0l = *(const short8v*)(wf + 1 * 512 + l * 8);
            const short8v w1h = *(const short8v*)(wf + 2 * 512 + l * 8);
            const short8v w1l = *(const short8v*)(wf + 3 * 512 + l * 8);

            // ---- sampling params for this lane's pixel (positions in regs)
            const float pyc = pyr[t], pxc = pxr[t];
            const float y0f = floorf(pyc), x0f = floorf(pxc);
            const float fy = pyc - y0f, fx = pxc - x0f;
            const int y0 = (int)y0f, x0 = (int)x0f;
            const bool vy0 = (unsigned)y0 < (unsigned)HDIM;
            const bool vy1 = (unsigned)(y0 + 1) < (unsigned)HDIM;
            const bool vx0 = (unsigned)x0 < (unsigned)WDIM;
            const bool vx1 = (unsigned)(x0 + 1) < (unsigned)WDIM;
            const int cy0 = min(max(y0, 0), HDIM - 1);
            const int cy1 = min(max(y0 + 1, 0), HDIM - 1);
            const int axc = min(max(x0, 0), WDIM - 2);
            const float wxL = vx0 ? (1.f - fx) : 0.f;
            const float wxR = vx1 ? fx : 0.f;
            float cgx, cgy;
            if (x0 < 0)              { cgx = wxR; cgy = 0.f; }
            else if (x0 >= WDIM - 1) { cgx = 0.f; cgy = wxL; }
            else                     { cgx = wxL; cgy = wxR; }
            const float wy0v = vy0 ? (1.f - fy) : 0.f;
            const float wy1v = vy1 ? fy : 0.f;
            const float a0  = wy0v * cgx, b0c = wy0v * cgy;
            const float a2  = wy1v * cgx, b2c = wy1v * cgy;

            const int r0 = cy0 - (h - 3), r1 = cy1 - (h - 3);
            const bool oob = ((unsigned)r0 > 7u) | ((unsigned)r1 > 7u);

            // ---- sample this lane's 8 channels
            float v[8];
            if (!oob) {
#pragma unroll
                for (int e = 0; e < 8; ++e) {
                    const float2u p0 = *(const float2u*)&Xw[r0][ch8 + e][axc];
                    const float2u p1 = *(const float2u*)&Xw[r1][ch8 + e][axc];
                    float s0 = p0.x * a0;
                    s0 = fmaf(p0.y, b0c, s0);
                    s0 = fmaf(p1.x, a2,  s0);
                    s0 = fmaf(p1.y, b2c, s0);
                    v[e] = s0;
                }
            } else {                         // statistically-never global path
                const int cbase = cg * 16 + ch8;
#pragma unroll
                for (int e = 0; e < 8; ++e) {
                    const float* xc = xb + (size_t)(cbase + e) * HW;
                    float s0 = xc[cy0 * WDIM + axc] * a0;
                    s0 = fmaf(xc[cy0 * WDIM + axc + 1], b0c, s0);
                    s0 = fmaf(xc[cy1 * WDIM + axc],     a2,  s0);
                    s0 = fmaf(xc[cy1 * WDIM + axc + 1], b2c, s0);
                    v[e] = s0;
                }
            }

            // ---- split bf16 hi/lo, pack to fragments
            short8v bh, bl;
#pragma unroll
            for (int e = 0; e < 8; ++e) {
                const short hs = f2bf(v[e]);
                bh[e] = hs;
                bl[e] = f2bf(v[e] - bf2f(hs));
            }

            acc0 = mfma_bf16(w0h, bh, acc0);
            acc1 = mfma_bf16(w1h, bh, acc1);
            acc0 = mfma_bf16(w0l, bh, acc0);
            acc1 = mfma_bf16(w1l, bh, acc1);
            acc0 = mfma_bf16(w0h, bl, acc0);
            acc1 = mfma_bf16(w1h, bl, acc1);
        }
    }

    // ---- epilogue: col=lane&31 (px), row=(r&3)+8*(r>>2)+4*(l>>5)
    float* op = out + (size_t)b * COUT * HW + h * WDIM + 32 * wv + (l & 31);
#pragma unroll
    for (int r = 0; r < 16; ++r) {
        const int oc0 = (r & 3) + 8 * (r >> 2) + 4 * (l >> 5);
        op[(size_t)oc0 * HW]        = acc0[r];
        op[(size_t)(oc0 + 32) * HW] = acc1[r];
    }
}

// ---------------------------------------------------------------------------
extern "C" void kernel_launch(void* const* d_in, const int* in_sizes, int n_in,
                              void* d_out, int out_size, void* d_ws, size_t ws_size,
                              hipStream_t stream)
{
    const float* x   = (const float*)d_in[0];
    const float* ow  = (const float*)d_in[1];
    const float* obi = (const float*)d_in[2];
    const float* wgt = (const float*)d_in[3];
    float* out = (float*)d_out;

    // ws layout: Wf (144 KB) | Wo (36 KB)
    short* Wf = (short*)d_ws;
    short* Wo = Wf + (size_t)72 * 2 * 512;

    wprep_all_kernel<<<dim3(108), 64, 0, stream>>>(wgt, ow, Wf, Wo);
    fused_deform_kernel<<<dim3(1024), 256, 0, stream>>>(x, Wf, Wo, obi, out);
}